// Round 1
// baseline (510.950 us; speedup 1.0000x reference)
//
#include <hip/hip_runtime.h>
#include <math.h>

#define V      128000
#define BEAM   3
#define HIST   16
#define NPART  125                       // partial-reduction blocks (125*256*4 = 128000)

// flat float32 output offsets (tuple concat order)
#define O_KV   0
#define O_IDX  100663296                 // 32*3*8*1024*128
#define O_SAVE (O_IDX + BEAM)            // +3
#define O_RP   (O_SAVE + BEAM*(HIST+1))  // +51
#define O_PROB (O_RP + BEAM*V)           // +384000
#define O_MAX  (O_PROB + BEAM)

__device__ __forceinline__ void ins3(float v, int idx,
    float& v0, int& i0, float& v1, int& i1, float& v2, int& i2) {
  if (v > v0)      { v2=v1; i2=i1; v1=v0; i1=i0; v0=v; i0=idx; }
  else if (v > v1) { v2=v1; i2=i1; v1=v;  i1=idx; }
  else if (v > v2) { v2=v;  i2=idx; }
}

// ---------------- phase A: per-block online-softmax + top3 partials ----------
__global__ __launch_bounds__(256) void topk_partial(const float* __restrict__ logits,
                                                    float* __restrict__ part) {
  const int gid  = blockIdx.x * 256 + threadIdx.x;      // float4 index, 0..31999
  const float4 x4 = ((const float4*)logits)[gid];
  const int base = gid << 2;

  float m = -INFINITY, s = 0.f;
  float v0 = -INFINITY, v1 = -INFINITY, v2 = -INFINITY;
  int   i0 = 0, i1 = 0, i2 = 0;

  float xs[4] = {x4.x, x4.y, x4.z, x4.w};
#pragma unroll
  for (int j = 0; j < 4; ++j) {
    const float x  = xs[j];
    const float nm = fmaxf(m, x);
    s = s * __expf(m - nm) + __expf(x - nm);
    m = nm;
    ins3(x, base + j, v0, i0, v1, i1, v2, i2);
  }

  const int lane = threadIdx.x & 63;
#pragma unroll
  for (int d = 32; d >= 1; d >>= 1) {
    float om  = __shfl_down(m,  d, 64);
    float os  = __shfl_down(s,  d, 64);
    float ov0 = __shfl_down(v0, d, 64); int oi0 = __shfl_down(i0, d, 64);
    float ov1 = __shfl_down(v1, d, 64); int oi1 = __shfl_down(i1, d, 64);
    float ov2 = __shfl_down(v2, d, 64); int oi2 = __shfl_down(i2, d, 64);
    if (lane + d < 64) {                 // guard: never merge wrapped/self data
      const float nm = fmaxf(m, om);
      s = s * __expf(m - nm) + os * __expf(om - nm);
      m = nm;
      ins3(ov0, oi0, v0, i0, v1, i1, v2, i2);
      ins3(ov1, oi1, v0, i0, v1, i1, v2, i2);
      ins3(ov2, oi2, v0, i0, v1, i1, v2, i2);
    }
  }

  __shared__ float sm[4][8];
  const int wave = threadIdx.x >> 6;
  if (lane == 0) {
    sm[wave][0] = m;  sm[wave][1] = s;
    sm[wave][2] = v0; sm[wave][3] = v1; sm[wave][4] = v2;
    sm[wave][5] = __int_as_float(i0);
    sm[wave][6] = __int_as_float(i1);
    sm[wave][7] = __int_as_float(i2);
  }
  __syncthreads();
  if (threadIdx.x == 0) {
#pragma unroll
    for (int w = 1; w < 4; ++w) {
      const float om = sm[w][0], os = sm[w][1];
      const float nm = fmaxf(m, om);
      s = s * __expf(m - nm) + os * __expf(om - nm);
      m = nm;
      ins3(sm[w][2], __float_as_int(sm[w][5]), v0, i0, v1, i1, v2, i2);
      ins3(sm[w][3], __float_as_int(sm[w][6]), v0, i0, v1, i1, v2, i2);
      ins3(sm[w][4], __float_as_int(sm[w][7]), v0, i0, v1, i1, v2, i2);
    }
    float* p = part + blockIdx.x * 8;
    p[0] = m;  p[1] = s;
    p[2] = v0; p[3] = v1; p[4] = v2;
    p[5] = __int_as_float(i0);
    p[6] = __int_as_float(i1);
    p[7] = __int_as_float(i2);
  }
}

// ---------------- phase B: merge partials, emit small outputs ----------------
__global__ __launch_bounds__(64) void topk_final(const float* __restrict__ part,
                                                 const int* __restrict__ save_id,
                                                 float* __restrict__ out,
                                                 int* __restrict__ ws_idx) {
  const int t = threadIdx.x;
  float m = -INFINITY, s = 0.f;
  float v0 = -INFINITY, v1 = -INFINITY, v2 = -INFINITY;
  int   i0 = 0, i1 = 0, i2 = 0;

  {
    const float* p = part + t * 8;           // t < 125 always (125 > 64? no: t<64<125)
    m = p[0]; s = p[1];
    v0 = p[2]; v1 = p[3]; v2 = p[4];
    i0 = __float_as_int(p[5]); i1 = __float_as_int(p[6]); i2 = __float_as_int(p[7]);
  }
  if (t + 64 < NPART) {
    const float* p = part + (t + 64) * 8;
    const float om = p[0], os = p[1];
    const float nm = fmaxf(m, om);
    s = s * __expf(m - nm) + os * __expf(om - nm);
    m = nm;
    ins3(p[2], __float_as_int(p[5]), v0, i0, v1, i1, v2, i2);
    ins3(p[3], __float_as_int(p[6]), v0, i0, v1, i1, v2, i2);
    ins3(p[4], __float_as_int(p[7]), v0, i0, v1, i1, v2, i2);
  }

#pragma unroll
  for (int d = 32; d >= 1; d >>= 1) {
    float om  = __shfl_down(m,  d, 64);
    float os  = __shfl_down(s,  d, 64);
    float ov0 = __shfl_down(v0, d, 64); int oi0 = __shfl_down(i0, d, 64);
    float ov1 = __shfl_down(v1, d, 64); int oi1 = __shfl_down(i1, d, 64);
    float ov2 = __shfl_down(v2, d, 64); int oi2 = __shfl_down(i2, d, 64);
    if (t + d < 64) {
      const float nm = fmaxf(m, om);
      s = s * __expf(m - nm) + os * __expf(om - nm);
      m = nm;
      ins3(ov0, oi0, v0, i0, v1, i1, v2, i2);
      ins3(ov1, oi1, v0, i0, v1, i1, v2, i2);
      ins3(ov2, oi2, v0, i0, v1, i1, v2, i2);
    }
  }

  __shared__ float res[BEAM];
  if (t == 0) {
    const float logZ = m + logf(s);
    out[O_IDX + 0] = (float)i0;
    out[O_IDX + 1] = (float)i1;
    out[O_IDX + 2] = (float)i2;
    out[O_PROB + 0] = v0 - logZ;
    out[O_PROB + 1] = v1 - logZ;
    out[O_PROB + 2] = v2 - logZ;
    out[O_MAX] = (float)i0;
    ws_idx[0] = i0; ws_idx[1] = i1; ws_idx[2] = i2;
    res[0] = (float)i0; res[1] = (float)i1; res[2] = (float)i2;
  }
  __syncthreads();
  if (t < BEAM * (HIST + 1)) {             // 51 elements of concat(save_id, idx)
    const int b = t / (HIST + 1);
    const int j = t - b * (HIST + 1);
    out[O_SAVE + t] = (j < HIST) ? (float)save_id[b * HIST + j] : res[b];
  }
}

// ---------------- phase C: KV beam-tile (read-once, write-3x) + penalty ------
// kv: 32 chunks of 2^18 float4 each; dst = 96 chunks.
#define KV_BLOCKS 32768                    // 32768*256 = 2^23 src float4
#define RP_BLOCKS 375                      // 375*256   = 96000 float4 = 3*128000 floats

__global__ __launch_bounds__(256) void kv_penalty(const float4* __restrict__ kv,
                                                  const float* __restrict__ rp,
                                                  const float* __restrict__ penv,
                                                  const int* __restrict__ ws_idx,
                                                  float4* __restrict__ kv_out,
                                                  float* __restrict__ rp_out) {
  const int b = blockIdx.x;
  if (b < KV_BLOCKS) {
    const int i     = (b << 8) | threadIdx.x;    // src float4 index
    const int chunk = i >> 18;                   // 0..31
    const int off   = i & 262143;
    const float4 v  = kv[i];
    const int dbase = (chunk * 3) << 18;
    kv_out[dbase + off]              = v;
    kv_out[dbase + (1 << 18) + off]  = v;
    kv_out[dbase + (2 << 18) + off]  = v;
  } else {
    const int i   = ((b - KV_BLOCKS) << 8) | threadIdx.x;  // float4 idx 0..95999
    const int row = i / 32000;                             // beam row
    const int off = i - row * 32000;
    float4 v = ((const float4*)(rp + row * V))[off];
    const int tgt = ws_idx[row];
    const int vb  = off << 2;
    if (tgt >= vb && tgt < vb + 4) {
      const float p = penv[0];
      float* vf = (float*)&v;
      vf[tgt - vb] *= p;
    }
    // O_RP is only 8B-aligned in the flat output -> float2 stores
    float2* d = (float2*)(rp_out + row * V) + off * 2;
    d[0] = make_float2(v.x, v.y);
    d[1] = make_float2(v.z, v.w);
  }
}

extern "C" void kernel_launch(void* const* d_in, const int* in_sizes, int n_in,
                              void* d_out, int out_size, void* d_ws, size_t ws_size,
                              hipStream_t stream) {
  const float* kv      = (const float*)d_in[0];
  const float* logits  = (const float*)d_in[1];
  const int*   save_id = (const int*)d_in[2];
  const float* rp      = (const float*)d_in[3];
  const float* penv    = (const float*)d_in[4];
  float* out = (float*)d_out;

  float* part  = (float*)d_ws;            // NPART*8 floats
  int* ws_idx  = (int*)d_ws + 2048;       // 3 ints, clear of partials

  topk_partial<<<NPART, 256, 0, stream>>>(logits, part);
  topk_final<<<1, 64, 0, stream>>>(part, save_id, out, ws_idx);
  kv_penalty<<<KV_BLOCKS + RP_BLOCKS, 256, 0, stream>>>(
      (const float4*)kv, rp, penv, ws_idx, (float4*)(out + O_KV), out + O_RP);
}